// Round 15
// baseline (185.347 us; speedup 1.0000x reference)
//
#include <hip/hip_runtime.h>
#include <hip/hip_bf16.h>
#include <cstdint>

// bf16 fragments as 8 x short (4 VGPRs) per cdna_hip_programming.md §3
typedef __attribute__((ext_vector_type(8))) short bf16x8;
typedef __attribute__((ext_vector_type(4))) float f32x4;
typedef __attribute__((ext_vector_type(16))) float f32x16;
typedef __attribute__((ext_vector_type(4))) uint16_t u16x4;

__device__ __forceinline__ uint16_t f2b(float f) {
  union { float f; uint32_t i; } v; v.f = f;
  return (uint16_t)((v.i + 0x7FFFu + ((v.i >> 16) & 1u)) >> 16);  // RNE
}

__device__ __forceinline__ uint32_t pkbf(float a, float b) {
  union { __hip_bfloat162 h2; uint32_t u; } c;
  c.h2 = __float22bfloat162_rn(make_float2(a, b));
  return c.u;   // low16 = a, high16 = b
}

// async global->LDS, 16B per lane; LDS dest is wave-uniform base + lane*16
#define GLDS16(g, l) __builtin_amdgcn_global_load_lds( \
    (const __attribute__((address_space(1))) void*)(g), \
    (__attribute__((address_space(3))) void*)(l), 16, 0, 0)

// counted vmcnt wait (literal immediate), with compiler memory fence
#define VMW(n) asm volatile("s_waitcnt vmcnt(" #n ")" ::: "memory")

// ---------------------------------------------------------------------------
// fp32 -> bf16 convert (RNE) for all three inputs in one launch
// ---------------------------------------------------------------------------
__global__ __launch_bounds__(256) void cvt_all(
    const float* __restrict__ x, const float* __restrict__ wa, const float* __restrict__ wp,
    uint16_t* __restrict__ xb, uint16_t* __restrict__ wab, uint16_t* __restrict__ wpb) {
  const int i = (blockIdx.x * 256 + threadIdx.x) * 4;
  const float* src; uint16_t* dst; int off;
  if (i < 4194304)      { src = x;  dst = xb;  off = i; }
  else if (i < 7340032) { src = wa; dst = wab; off = i - 4194304; }
  else                  { src = wp; dst = wpb; off = i - 7340032; }
  const float4 v = *(const float4*)(src + off);
  u16x4 o;
  o.x = f2b(v.x); o.y = f2b(v.y); o.z = f2b(v.z); o.w = f2b(v.w);
  *(u16x4*)(dst + off) = o;
}

// ---------------------------------------------------------------------------
// C[M,N] = A[M,K] @ B[N,K]^T + bias[N]. A,B bf16, bias fp32, fp32 accumulate.
// PIPELINED K-loop (T3+T4): BK=32, 3 LDS buffers, depth-2 prefetch, counted
// vmcnt (never 0 in-loop) via raw s_barrier + asm. setprio(1) on MFMA (T5).
// Granule XOR swizzle (T2, rule #21): staging pre-swizzles the GLOBAL source
// (seg = (flat&3) ^ ((flat>>3)&3)); fragment reads use g = q4 ^ ((row>>1)&3)
// -> 2 lanes/bank (HW minimum, free per m136) instead of 8-way conflict.
// Epilogues: bf16 = LDS-transposed b128 stores; fp32 = direct 64B-coalesced.
// ---------------------------------------------------------------------------
template <int BM, int BN, bool OUT_BF16>
__global__ __launch_bounds__(256, BN == 128 ? 3 : 4) void gemm_bt_bias(
    const uint16_t* __restrict__ A, const uint16_t* __restrict__ B,
    const float* __restrict__ bias, void* __restrict__ Cv,
    int M, int N, int K) {
  constexpr int MI = BM / 32;            // acc row-tiles per wave
  constexpr int NJ = BN / 32;            // acc col-tiles per wave
  constexpr int CA = BM / 16;            // A chunks per K-step (16 rows x 32K each)
  constexpr int CB = BN / 16;            // B chunks per K-step
  constexpr int CPW = (CA + CB) / 4;     // GLDS16 per thread per K-step (4 or 3)
  constexpr int ABLK = BM * 32;          // u16 per A sub-tile
  constexpr int BUFSZ = (BM + BN) * 32;  // u16 per buffer
  constexpr size_t ST_BYTES = (size_t)3 * BUFSZ * 2;
  constexpr size_t CT_BYTES = OUT_BF16 ? (size_t)4 * (BM / 2) * 72 * 2 : 0;
  constexpr size_t LB = CT_BYTES > ST_BYTES ? CT_BYTES : ST_BYTES;
  __shared__ alignas(16) unsigned char ldsb[LB];
  uint16_t* lds = (uint16_t*)ldsb;

  const int tid = threadIdx.x;
  const int wave = tid >> 6, lane = tid & 63;
  const int q4 = lane >> 4, l16 = lane & 15;
  const int wm = wave >> 1, wn = wave & 1;
  const long blockM = (long)blockIdx.y * BM;
  const long blockN = (long)blockIdx.x * BN;
  const int NK = K >> 5;                 // K-steps of 32

  f32x4 acc[MI][NJ] = {};

  auto STAGE = [&](int s) {
    uint16_t* buf = lds + (s % 3) * BUFSZ;
#pragma unroll
    for (int c = 0; c < CPW; ++c) {
      const int id = c * 4 + wave;       // wave-uniform
      const uint16_t* mat; long rowBase; int a, off;
      if (id < CA) { mat = A; rowBase = blockM; a = id;      off = a * 512; }
      else         { mat = B; rowBase = blockN; a = id - CA; off = ABLK + a * 512; }
      const int flat = a * 64 + lane;
      const int row = flat >> 2;
      const int seg = (flat & 3) ^ ((flat >> 3) & 3);   // pre-swizzled source
      GLDS16(mat + (rowBase + row) * (long)K + s * 32 + seg * 8, buf + off);
    }
  };

  STAGE(0);
  STAGE(1);
  for (int s = 0; s < NK; ++s) {
    if (s + 2 < NK) STAGE(s + 2);        // into buf freed by end-barrier of s-1
    __builtin_amdgcn_sched_barrier(0);
    if (s + 2 < NK) {                    // outstanding: stage(s+1), stage(s+2)
      if constexpr (CPW == 4) VMW(8); else VMW(6);
    } else if (s + 2 == NK) {            // outstanding: stage(s+1)
      if constexpr (CPW == 4) VMW(4); else VMW(3);
    } else {
      VMW(0);
    }
    __builtin_amdgcn_sched_barrier(0);
    __builtin_amdgcn_s_barrier();        // everyone's stage(s) landed
    const uint16_t* Ah = lds + (s % 3) * BUFSZ;
    const uint16_t* Bh = Ah + ABLK;
    bf16x8 af[MI], bfr[NJ];
#pragma unroll
    for (int i = 0; i < MI; ++i) {
      const int row = wm * (BM / 2) + i * 16 + l16;
      const int g = q4 ^ ((row >> 1) & 3);             // swizzled granule
      af[i] = *(const bf16x8*)&Ah[row * 32 + g * 8];
    }
#pragma unroll
    for (int j = 0; j < NJ; ++j) {
      const int row = wn * (BN / 2) + j * 16 + l16;
      const int g = q4 ^ ((row >> 1) & 3);
      bfr[j] = *(const bf16x8*)&Bh[row * 32 + g * 8];
    }
    __builtin_amdgcn_s_setprio(1);
#pragma unroll
    for (int i = 0; i < MI; ++i)
#pragma unroll
      for (int j = 0; j < NJ; ++j)
        acc[i][j] = __builtin_amdgcn_mfma_f32_16x16x32_bf16(af[i], bfr[j], acc[i][j], 0, 0, 0);
    __builtin_amdgcn_s_setprio(0);
    __builtin_amdgcn_s_barrier();        // reads of buf[s%3] done -> restageable
  }
  __syncthreads();                       // full drain before LDS reuse / exit

  // epilogue: acc (C/D layout: col=l16, row=q4*4+r)
  if constexpr (OUT_BF16) {
    // LDS-transposed vector stores (BN=128 path, verified)
    uint16_t* ct = lds + wave * (BM / 2) * 72;
#pragma unroll
    for (int j = 0; j < NJ; ++j) {
      const float bv = bias[blockN + wn * (BN / 2) + j * 16 + l16];
#pragma unroll
      for (int i = 0; i < MI; ++i)
#pragma unroll
        for (int r = 0; r < 4; ++r)
          ct[(i * 16 + q4 * 4 + r) * 72 + j * 16 + l16] = f2b(acc[i][j][r] + bv);
    }
    __syncthreads();
    uint16_t* Cb = (uint16_t*)Cv;
#pragma unroll
    for (int st = 0; st < BM / 16; ++st) {
      const int flat = st * 64 + lane;
      const int row = flat >> 3, seg = flat & 7;
      const bf16x8 v = *(const bf16x8*)&ct[row * 72 + seg * 8];
      *(bf16x8*)&Cb[(blockM + wm * (BM / 2) + row) * (long)N + blockN + wn * 64 + seg * 8] = v;
    }
  } else {
    // direct fp32 stores: quad q4 writes 16 consecutive cols (64B segments)
    float* Cb = (float*)Cv;
#pragma unroll
    for (int j = 0; j < NJ; ++j) {
      const long col = blockN + wn * (BN / 2) + j * 16 + l16;
      const float bv = bias[col];
#pragma unroll
      for (int i = 0; i < MI; ++i)
#pragma unroll
        for (int r = 0; r < 4; ++r) {
          const long row = blockM + wm * (BM / 2) + i * 16 + q4 * 4 + r;
          Cb[row * (long)N + col] = acc[i][j][r] + bv;
        }
    }
  }
}

// ---------------------------------------------------------------------------
// Flash-style causal attention, S^T form, 32x32x16 MFMA, in-block split-K,
// barrier-free tiles. NEW: K never goes through LDS — wave w's kf fragment
// (K[key0+l32][m*16+hh*8..]) is loaded DIRECTLY from global as 4 b128
// gathers (32 rows x 32B, L2-resident: 256KB/head, 4 heads/XCD), prefetched
// one tile ahead so L2 latency hides under softmax+PV of the prior tile.
// Deletes 4 ds_write + 4 ds_read + 4 coalesced loads per tile-wave (chain
// shortening; the r7-r11 evidence says scheduling isn't the cap, chain is).
// V path / softmax / permlane P-exchange / merge unchanged (r11-verified).
// Vt and the merge overlay share LDS (34.8KB), protected by merge barrier.
// NaN guard: pm floored at -3e4. bh in LOW bits for XCD L2 locality.
// ---------------------------------------------------------------------------
__global__ __launch_bounds__(256, 2) void attn_flash(
    const uint16_t* __restrict__ kqv, uint16_t* __restrict__ attn) {
  constexpr int T = 2048, C = 1024, C3 = 3072;
  __shared__ alignas(16) unsigned char ldsb[34816];
  uint16_t* Vt = (uint16_t*)ldsb;             // [64][136] u16, rot-16 swizzle
  uint32_t* VtW = (uint32_t*)ldsb;            // pitch 68 dwords
  float* mlb  = (float*)ldsb;                 // [4][2][32] (merge overlay)
  float* obuf = (float*)(ldsb + 1024);        // [4][32][66] f32 (merge overlay)

  const int tid = threadIdx.x;
  const int wave = tid >> 6, lane = tid & 63;
  const int l32 = lane & 31, hh = lane >> 5;
  const int sidx = blockIdx.x >> 5, bh = blockIdx.x & 31;
  const int b = bh >> 4, h = bh & 15;
  const size_t base = (size_t)b * T * C3;
  const int hD = h * 64;
  const int lr = lane >> 3, kch = lane & 7;   // per-wave V staging coords
  const float sc = 0.125f * 1.4426950408889634f;  // D^-0.5 * log2(e)

  const int qb = 31 - sidx;            // big strips first (backfill order)
  const int dd = qb * 64 + 63 - wave * 32;
  const int nktw = (dd < 0) ? 0 : ((dd >> 7) + 1);

  // Q regs: qf[qc][m], B-frag col=l32, k=hh*8+j
  bf16x8 qf[2][4];
#pragma unroll
  for (int qc = 0; qc < 2; ++qc)
#pragma unroll
    for (int m = 0; m < 4; ++m)
      qf[qc][m] = *(const bf16x8*)&kqv[base + (size_t)(qb * 64 + qc * 32 + l32) * C3 + C + hD + m * 16 + hh * 8];

  f32x16 o[2][2] = {};   // [qc][db]: O[q=qc*32+(r&3)+8*(r>>2)+4*hh][d=db*32+l32]
  float m_i[2] = {-1e30f, -1e30f}, l_i[2] = {0.f, 0.f};

  // prefetch own slice of tile 0: kf directly (gather), V for LDS transpose
  bf16x8 kfn[4], pv0[2], pv1[2];
  if (nktw > 0) {
    const int kb0 = wave * 32;
#pragma unroll
    for (int m = 0; m < 4; ++m)
      kfn[m] = *(const bf16x8*)&kqv[base + (size_t)(kb0 + l32) * C3 + hD + m * 16 + hh * 8];
#pragma unroll
    for (int s2 = 0; s2 < 2; ++s2) {
      const size_t gg = base + (size_t)(kb0 + 2 * (s2 * 8 + lr)) * C3 + 2 * C + hD + kch * 8;
      pv0[s2] = *(const bf16x8*)&kqv[gg];
      pv1[s2] = *(const bf16x8*)&kqv[gg + C3];
    }
  }

  for (int kt = 0; kt < nktw; ++kt) {
    const int key0 = kt * 128 + wave * 32;
    // stage own V slice transposed: pack key-pairs, rot-16 swizzle
#pragma unroll
    for (int s2 = 0; s2 < 2; ++s2) {
      const int colw = (wave * 16 + s2 * 8 + lr + 8 * kch) & 63;
      const uint32_t* a0 = (const uint32_t*)&pv0[s2];
      const uint32_t* a1 = (const uint32_t*)&pv1[s2];
#pragma unroll
      for (int i = 0; i < 8; ++i) {
        const uint32_t w = (i & 1)
            ? __builtin_amdgcn_perm(a1[i >> 1], a0[i >> 1], 0x07060302u)
            : __builtin_amdgcn_perm(a1[i >> 1], a0[i >> 1], 0x05040100u);
        VtW[(kch * 8 + i) * 68 + colw] = w;
      }
    }
    // current kf from prefetch regs; issue next tile's kf gather + V loads
    bf16x8 kf[4];
#pragma unroll
    for (int m = 0; m < 4; ++m) kf[m] = kfn[m];
    if (kt + 1 < nktw) {
      const int kb2 = (kt + 1) * 128 + wave * 32;
#pragma unroll
      for (int m = 0; m < 4; ++m)
        kfn[m] = *(const bf16x8*)&kqv[base + (size_t)(kb2 + l32) * C3 + hD + m * 16 + hh * 8];
#pragma unroll
      for (int s2 = 0; s2 < 2; ++s2) {
        const size_t gg = base + (size_t)(kb2 + 2 * (s2 * 8 + lr)) * C3 + 2 * C + hD + kch * 8;
        pv0[s2] = *(const bf16x8*)&kqv[gg];
        pv1[s2] = *(const bf16x8*)&kqv[gg + C3];
      }
    }

#pragma unroll
    for (int qc = 0; qc < 2; ++qc) {
      // skip: slice fully masked for this q-half (wave-uniform)
      if (key0 > qb * 64 + qc * 32 + 31) continue;
      // S^T = K·Q^T : 32 keys x 32 q; lane holds S^T[key(r,hh)][q=l32]
      f32x16 z = {};
#pragma unroll
      for (int m = 0; m < 4; ++m)
        z = __builtin_amdgcn_mfma_f32_32x32x16_bf16(kf[m], qf[qc][m], z, 0, 0, 0);
      if (key0 + 31 > qb * 64 + qc * 32) {   // diagonal band: elementwise mask
        const int qg = qb * 64 + qc * 32 + l32;
#pragma unroll
        for (int r = 0; r < 16; ++r) {
          const int kg = key0 + (r & 3) + 8 * (r >> 2) + 4 * hh;
          if (kg > qg) z[r] = -1e30f;
        }
      }
      // online softmax over this wave's 32 keys; tree max (depth 4)
      float t8[8];
#pragma unroll
      for (int r = 0; r < 8; ++r) t8[r] = fmaxf(z[r], z[r + 8]);
#pragma unroll
      for (int r = 0; r < 4; ++r) t8[r] = fmaxf(t8[r], t8[r + 4]);
      float mloc = fmaxf(fmaxf(t8[0], t8[1]), fmaxf(t8[2], t8[3]));
      mloc = fmaxf(mloc, __shfl_xor(mloc, 32, 64));
      const float pm = fmaxf(mloc * sc, -3.0e4f);   // NaN-guard floor
      if (__any(pm - m_i[qc] > 8.0f)) {   // defer-max
        const float mnew = fmaxf(m_i[qc], pm);
        const float alpha = exp2f(m_i[qc] - mnew);
#pragma unroll
        for (int r = 0; r < 16; ++r) {
          const float ar = __shfl(alpha, (r & 3) + 8 * (r >> 2) + 4 * hh, 64);
          o[qc][0][r] *= ar;
          o[qc][1][r] *= ar;
        }
        l_i[qc] *= alpha;
        m_i[qc] = mnew;
      }
#pragma unroll
      for (int r = 0; r < 16; ++r)
        z[r] = exp2f(fmaf(z[r], sc, -m_i[qc]));
      float s8[8];   // tree sum (depth 4)
#pragma unroll
      for (int r = 0; r < 8; ++r) s8[r] = z[r] + z[r + 8];
#pragma unroll
      for (int r = 0; r < 4; ++r) s8[r] += s8[r + 4];
      float rs = (s8[0] + s8[1]) + (s8[2] + s8[3]);
      rs += __shfl_xor(rs, 32, 64);
      l_i[qc] += rs;

      // O += P·V : pack P to bf16; lane-half exchange via permlane32_swap
      // (vdst.hi <-> src.lo): x' = {x.lo, y.lo}, y' = {x.hi, y.hi}
      uint32_t x0 = pkbf(z[0], z[1]),   x1 = pkbf(z[2], z[3]);
      uint32_t y0 = pkbf(z[4], z[5]),   y1 = pkbf(z[6], z[7]);
      uint32_t x2 = pkbf(z[8], z[9]),   x3 = pkbf(z[10], z[11]);
      uint32_t y2 = pkbf(z[12], z[13]), y3 = pkbf(z[14], z[15]);
      asm volatile("v_permlane32_swap_b32 %0, %1" : "+v"(x0), "+v"(y0));
      asm volatile("v_permlane32_swap_b32 %0, %1" : "+v"(x1), "+v"(y1));
      asm volatile("v_permlane32_swap_b32 %0, %1" : "+v"(x2), "+v"(y2));
      asm volatile("v_permlane32_swap_b32 %0, %1" : "+v"(x3), "+v"(y3));
#pragma unroll
      for (int cc = 0; cc < 2; ++cc) {
        union { bf16x8 v; uint32_t w[4]; } pa;
        if (cc == 0) { pa.w[0] = x0; pa.w[1] = x1; pa.w[2] = y0; pa.w[3] = y1; }
        else         { pa.w[0] = x2; pa.w[1] = x3; pa.w[2] = y2; pa.w[3] = y3; }
#pragma unroll
        for (int db = 0; db < 2; ++db) {
          const int d = db * 32 + l32;
          const int col = (wave * 32 + cc * 16 + hh * 8 + 16 * (d >> 3)) & 127;
          const bf16x8 vf = *(const bf16x8*)&Vt[d * 136 + col];
          o[qc][db] = __builtin_amdgcn_mfma_f32_32x32x16_bf16(pa.v, vf, o[qc][db], 0, 0, 0);
        }
      }
    }
  }

  // ---- in-block merge of 4 per-wave partials, one qc-half at a time ----
#pragma unroll
  for (int qc = 0; qc < 2; ++qc) {
    __syncthreads();   // all waves' tiles done (qc=0) / obuf reads done (qc=1)
    if (hh == 0) {
      mlb[wave * 64 + l32] = m_i[qc];
      mlb[wave * 64 + 32 + l32] = l_i[qc];
    }
#pragma unroll
    for (int r = 0; r < 16; ++r) {
      const int ql = (r & 3) + 8 * (r >> 2) + 4 * hh;
      const int bw = wave * 2112 + ql * 66 + l32;
      obuf[bw] = o[qc][0][r];
      obuf[bw + 32] = o[qc][1][r];
    }
    __syncthreads();
    // sum phase: thread = (row q = l32, col-block cb = wave*2+hh)
    float mw[4], lw[4];
#pragma unroll
    for (int w = 0; w < 4; ++w) {
      mw[w] = mlb[w * 64 + l32];
      lw[w] = mlb[w * 64 + 32 + l32];
    }
    const float M = fmaxf(fmaxf(mw[0], mw[1]), fmaxf(mw[2], mw[3]));
    float L = 0.f, ww[4];
#pragma unroll
    for (int w = 0; w < 4; ++w) { ww[w] = exp2f(mw[w] - M); L += lw[w] * ww[w]; }
    const float Li = 1.0f / L;
    const int cb = wave * 2 + hh;
    float acc[8] = {};
#pragma unroll
    for (int w = 0; w < 4; ++w)
#pragma unroll
      for (int p = 0; p < 4; ++p) {
        const float2 v = *(const float2*)&obuf[w * 2112 + l32 * 66 + cb * 8 + p * 2];
        acc[2 * p]     += v.x * ww[w];
        acc[2 * p + 1] += v.y * ww[w];
      }
    union { bf16x8 v; uint32_t w4[4]; } ov;
#pragma unroll
    for (int p = 0; p < 4; ++p)
      ov.w4[p] = pkbf(acc[2 * p] * Li, acc[2 * p + 1] * Li);
    *(bf16x8*)&attn[((size_t)b * T + qb * 64 + qc * 32 + l32) * C + hD + cb * 8] = ov.v;
  }
}

extern "C" void kernel_launch(void* const* d_in, const int* in_sizes, int n_in,
                              void* d_out, int out_size, void* d_ws, size_t ws_size,
                              hipStream_t stream) {
  const float* x      = (const float*)d_in[0];  // (2,2048,1024) fp32
  const float* w_attn = (const float*)d_in[1];  // (3072,1024)  fp32
  const float* b_attn = (const float*)d_in[2];  // (3072,)      fp32
  const float* w_proj = (const float*)d_in[3];  // (1024,1024)  fp32
  const float* b_proj = (const float*)d_in[4];  // (1024,)      fp32
  float* out = (float*)d_out;                   // (2,2048,1024) fp32

  // ws layout (bf16): xb | wab | wpb | kqv | attnb
  uint16_t* xb    = (uint16_t*)d_ws;                     // 4096*1024
  uint16_t* wab   = xb  + (size_t)4096 * 1024;           // 3072*1024
  uint16_t* wpb   = wab + (size_t)3072 * 1024;           // 1024*1024
  uint16_t* kqv   = wpb + (size_t)1024 * 1024;           // 4096*3072
  uint16_t* attnb = kqv + (size_t)4096 * 3072;           // 4096*1024

  dim3 blk(256, 1, 1);
  hipLaunchKernelGGL(cvt_all, dim3(8192), blk, 0, stream, x, w_attn, w_proj, xb, wab, wpb);

  hipLaunchKernelGGL((gemm_bt_bias<128, 128, true>), dim3(3072 / 128, 4096 / 128, 1), blk, 0, stream,
                     xb, wab, b_attn, (void*)kqv, 4096, 3072, 1024);
  hipLaunchKernelGGL(attn_flash, dim3(1024, 1, 1), blk, 0, stream, kqv, attnb);
  hipLaunchKernelGGL((gemm_bt_bias<128, 64, false>), dim3(1024 / 64, 4096 / 128, 1), blk, 0, stream,
                     attnb, wpb, b_proj, (void*)out, 4096, 1024, 1024);
}

// Round 16
// 181.805 us; speedup vs baseline: 1.0195x; 1.0195x over previous
//
#include <hip/hip_runtime.h>
#include <hip/hip_bf16.h>
#include <cstdint>

// bf16 fragments as 8 x short (4 VGPRs) per cdna_hip_programming.md §3
typedef __attribute__((ext_vector_type(8))) short bf16x8;
typedef __attribute__((ext_vector_type(4))) float f32x4;
typedef __attribute__((ext_vector_type(16))) float f32x16;
typedef __attribute__((ext_vector_type(4))) uint16_t u16x4;

__device__ __forceinline__ uint16_t f2b(float f) {
  union { float f; uint32_t i; } v; v.f = f;
  return (uint16_t)((v.i + 0x7FFFu + ((v.i >> 16) & 1u)) >> 16);  // RNE
}

__device__ __forceinline__ uint32_t pkbf(float a, float b) {
  union { __hip_bfloat162 h2; uint32_t u; } c;
  c.h2 = __float22bfloat162_rn(make_float2(a, b));
  return c.u;   // low16 = a, high16 = b
}

// async global->LDS, 16B per lane; LDS dest is wave-uniform base + lane*16
#define GLDS16(g, l) __builtin_amdgcn_global_load_lds( \
    (const __attribute__((address_space(1))) void*)(g), \
    (__attribute__((address_space(3))) void*)(l), 16, 0, 0)

// counted vmcnt wait (literal immediate), with compiler memory fence
#define VMW(n) asm volatile("s_waitcnt vmcnt(" #n ")" ::: "memory")

// ---------------------------------------------------------------------------
// fp32 -> bf16 convert (RNE) for all three inputs in one launch
// ---------------------------------------------------------------------------
__global__ __launch_bounds__(256) void cvt_all(
    const float* __restrict__ x, const float* __restrict__ wa, const float* __restrict__ wp,
    uint16_t* __restrict__ xb, uint16_t* __restrict__ wab, uint16_t* __restrict__ wpb) {
  const int i = (blockIdx.x * 256 + threadIdx.x) * 4;
  const float* src; uint16_t* dst; int off;
  if (i < 4194304)      { src = x;  dst = xb;  off = i; }
  else if (i < 7340032) { src = wa; dst = wab; off = i - 4194304; }
  else                  { src = wp; dst = wpb; off = i - 7340032; }
  const float4 v = *(const float4*)(src + off);
  u16x4 o;
  o.x = f2b(v.x); o.y = f2b(v.y); o.z = f2b(v.z); o.w = f2b(v.w);
  *(u16x4*)(dst + off) = o;
}

// ---------------------------------------------------------------------------
// C[M,N] = A[M,K] @ B[N,K]^T + bias[N]. A,B bf16, bias fp32, fp32 accumulate.
// PIPELINED K-loop (T3+T4): BK=32, 3 LDS buffers, depth-2 prefetch, counted
// vmcnt (never 0 in-loop) via raw s_barrier + asm. setprio(1) on MFMA (T5).
// Granule XOR swizzle (T2, rule #21): staging pre-swizzles the GLOBAL source
// (seg = (flat&3) ^ ((flat>>3)&3)); fragment reads use g = q4 ^ ((row>>1)&3)
// -> 2 lanes/bank (HW minimum, free per m136) instead of 8-way conflict.
// Epilogues: bf16 = LDS-transposed b128 stores; fp32 = direct 64B-coalesced.
// ---------------------------------------------------------------------------
template <int BM, int BN, bool OUT_BF16>
__global__ __launch_bounds__(256, BN == 128 ? 3 : 4) void gemm_bt_bias(
    const uint16_t* __restrict__ A, const uint16_t* __restrict__ B,
    const float* __restrict__ bias, void* __restrict__ Cv,
    int M, int N, int K) {
  constexpr int MI = BM / 32;            // acc row-tiles per wave
  constexpr int NJ = BN / 32;            // acc col-tiles per wave
  constexpr int CA = BM / 16;            // A chunks per K-step (16 rows x 32K each)
  constexpr int CB = BN / 16;            // B chunks per K-step
  constexpr int CPW = (CA + CB) / 4;     // GLDS16 per thread per K-step (4 or 3)
  constexpr int ABLK = BM * 32;          // u16 per A sub-tile
  constexpr int BUFSZ = (BM + BN) * 32;  // u16 per buffer
  constexpr size_t ST_BYTES = (size_t)3 * BUFSZ * 2;
  constexpr size_t CT_BYTES = OUT_BF16 ? (size_t)4 * (BM / 2) * 72 * 2 : 0;
  constexpr size_t LB = CT_BYTES > ST_BYTES ? CT_BYTES : ST_BYTES;
  __shared__ alignas(16) unsigned char ldsb[LB];
  uint16_t* lds = (uint16_t*)ldsb;

  const int tid = threadIdx.x;
  const int wave = tid >> 6, lane = tid & 63;
  const int q4 = lane >> 4, l16 = lane & 15;
  const int wm = wave >> 1, wn = wave & 1;
  const long blockM = (long)blockIdx.y * BM;
  const long blockN = (long)blockIdx.x * BN;
  const int NK = K >> 5;                 // K-steps of 32

  f32x4 acc[MI][NJ] = {};

  auto STAGE = [&](int s) {
    uint16_t* buf = lds + (s % 3) * BUFSZ;
#pragma unroll
    for (int c = 0; c < CPW; ++c) {
      const int id = c * 4 + wave;       // wave-uniform
      const uint16_t* mat; long rowBase; int a, off;
      if (id < CA) { mat = A; rowBase = blockM; a = id;      off = a * 512; }
      else         { mat = B; rowBase = blockN; a = id - CA; off = ABLK + a * 512; }
      const int flat = a * 64 + lane;
      const int row = flat >> 2;
      const int seg = (flat & 3) ^ ((flat >> 3) & 3);   // pre-swizzled source
      GLDS16(mat + (rowBase + row) * (long)K + s * 32 + seg * 8, buf + off);
    }
  };

  STAGE(0);
  STAGE(1);
  for (int s = 0; s < NK; ++s) {
    if (s + 2 < NK) STAGE(s + 2);        // into buf freed by end-barrier of s-1
    __builtin_amdgcn_sched_barrier(0);
    if (s + 2 < NK) {                    // outstanding: stage(s+1), stage(s+2)
      if constexpr (CPW == 4) VMW(8); else VMW(6);
    } else if (s + 2 == NK) {            // outstanding: stage(s+1)
      if constexpr (CPW == 4) VMW(4); else VMW(3);
    } else {
      VMW(0);
    }
    __builtin_amdgcn_sched_barrier(0);
    __builtin_amdgcn_s_barrier();        // everyone's stage(s) landed
    const uint16_t* Ah = lds + (s % 3) * BUFSZ;
    const uint16_t* Bh = Ah + ABLK;
    bf16x8 af[MI], bfr[NJ];
#pragma unroll
    for (int i = 0; i < MI; ++i) {
      const int row = wm * (BM / 2) + i * 16 + l16;
      const int g = q4 ^ ((row >> 1) & 3);             // swizzled granule
      af[i] = *(const bf16x8*)&Ah[row * 32 + g * 8];
    }
#pragma unroll
    for (int j = 0; j < NJ; ++j) {
      const int row = wn * (BN / 2) + j * 16 + l16;
      const int g = q4 ^ ((row >> 1) & 3);
      bfr[j] = *(const bf16x8*)&Bh[row * 32 + g * 8];
    }
    __builtin_amdgcn_s_setprio(1);
#pragma unroll
    for (int i = 0; i < MI; ++i)
#pragma unroll
      for (int j = 0; j < NJ; ++j)
        acc[i][j] = __builtin_amdgcn_mfma_f32_16x16x32_bf16(af[i], bfr[j], acc[i][j], 0, 0, 0);
    __builtin_amdgcn_s_setprio(0);
    __builtin_amdgcn_s_barrier();        // reads of buf[s%3] done -> restageable
  }
  __syncthreads();                       // full drain before LDS reuse / exit

  // epilogue: acc (C/D layout: col=l16, row=q4*4+r)
  if constexpr (OUT_BF16) {
    // LDS-transposed vector stores (BN=128 path, verified)
    uint16_t* ct = lds + wave * (BM / 2) * 72;
#pragma unroll
    for (int j = 0; j < NJ; ++j) {
      const float bv = bias[blockN + wn * (BN / 2) + j * 16 + l16];
#pragma unroll
      for (int i = 0; i < MI; ++i)
#pragma unroll
        for (int r = 0; r < 4; ++r)
          ct[(i * 16 + q4 * 4 + r) * 72 + j * 16 + l16] = f2b(acc[i][j][r] + bv);
    }
    __syncthreads();
    uint16_t* Cb = (uint16_t*)Cv;
#pragma unroll
    for (int st = 0; st < BM / 16; ++st) {
      const int flat = st * 64 + lane;
      const int row = flat >> 3, seg = flat & 7;
      const bf16x8 v = *(const bf16x8*)&ct[row * 72 + seg * 8];
      *(bf16x8*)&Cb[(blockM + wm * (BM / 2) + row) * (long)N + blockN + wn * 64 + seg * 8] = v;
    }
  } else {
    // direct fp32 stores: quad q4 writes 16 consecutive cols (64B segments)
    float* Cb = (float*)Cv;
#pragma unroll
    for (int j = 0; j < NJ; ++j) {
      const long col = blockN + wn * (BN / 2) + j * 16 + l16;
      const float bv = bias[col];
#pragma unroll
      for (int i = 0; i < MI; ++i)
#pragma unroll
        for (int r = 0; r < 4; ++r) {
          const long row = blockM + wm * (BM / 2) + i * 16 + q4 * 4 + r;
          Cb[row * (long)N + col] = acc[i][j][r] + bv;
        }
    }
  }
}

// ---------------------------------------------------------------------------
// Flash-style causal attention, S^T form, 32x32x16 MFMA, in-block split-K,
// barrier-free tiles, direct-from-L2 K fragments (r15). NEW: the PV
// V-fragment reads (vf) are HOISTED out of the qc loop — they depend only on
// (wave, cc, db), not qc, and Vt is not written between qc iterations, but
// the compiler cannot CSE LDS loads across the softmax code. This halves PV
// LDS b128 traffic (8 -> 4 reads/tile-wave) and its bank conflicts, which
// r15 isolated as THE conflict source (count unchanged when K path removed:
// all 3.21M cycles are V-side, ~6 extra cyc per vf read).
// V path / softmax / permlane P-exchange / merge unchanged (r11-verified).
// NaN guard: pm floored at -3e4. bh in LOW bits for XCD L2 locality.
// ---------------------------------------------------------------------------
__global__ __launch_bounds__(256, 2) void attn_flash(
    const uint16_t* __restrict__ kqv, uint16_t* __restrict__ attn) {
  constexpr int T = 2048, C = 1024, C3 = 3072;
  __shared__ alignas(16) unsigned char ldsb[34816];
  uint16_t* Vt = (uint16_t*)ldsb;             // [64][136] u16, rot-16 swizzle
  uint32_t* VtW = (uint32_t*)ldsb;            // pitch 68 dwords
  float* mlb  = (float*)ldsb;                 // [4][2][32] (merge overlay)
  float* obuf = (float*)(ldsb + 1024);        // [4][32][66] f32 (merge overlay)

  const int tid = threadIdx.x;
  const int wave = tid >> 6, lane = tid & 63;
  const int l32 = lane & 31, hh = lane >> 5;
  const int sidx = blockIdx.x >> 5, bh = blockIdx.x & 31;
  const int b = bh >> 4, h = bh & 15;
  const size_t base = (size_t)b * T * C3;
  const int hD = h * 64;
  const int lr = lane >> 3, kch = lane & 7;   // per-wave V staging coords
  const float sc = 0.125f * 1.4426950408889634f;  // D^-0.5 * log2(e)

  const int qb = 31 - sidx;            // big strips first (backfill order)
  const int dd = qb * 64 + 63 - wave * 32;
  const int nktw = (dd < 0) ? 0 : ((dd >> 7) + 1);

  // Q regs: qf[qc][m], B-frag col=l32, k=hh*8+j
  bf16x8 qf[2][4];
#pragma unroll
  for (int qc = 0; qc < 2; ++qc)
#pragma unroll
    for (int m = 0; m < 4; ++m)
      qf[qc][m] = *(const bf16x8*)&kqv[base + (size_t)(qb * 64 + qc * 32 + l32) * C3 + C + hD + m * 16 + hh * 8];

  f32x16 o[2][2] = {};   // [qc][db]: O[q=qc*32+(r&3)+8*(r>>2)+4*hh][d=db*32+l32]
  float m_i[2] = {-1e30f, -1e30f}, l_i[2] = {0.f, 0.f};

  // prefetch own slice of tile 0: kf directly (gather), V for LDS transpose
  bf16x8 kfn[4], pv0[2], pv1[2];
  if (nktw > 0) {
    const int kb0 = wave * 32;
#pragma unroll
    for (int m = 0; m < 4; ++m)
      kfn[m] = *(const bf16x8*)&kqv[base + (size_t)(kb0 + l32) * C3 + hD + m * 16 + hh * 8];
#pragma unroll
    for (int s2 = 0; s2 < 2; ++s2) {
      const size_t gg = base + (size_t)(kb0 + 2 * (s2 * 8 + lr)) * C3 + 2 * C + hD + kch * 8;
      pv0[s2] = *(const bf16x8*)&kqv[gg];
      pv1[s2] = *(const bf16x8*)&kqv[gg + C3];
    }
  }

  for (int kt = 0; kt < nktw; ++kt) {
    const int key0 = kt * 128 + wave * 32;
    // stage own V slice transposed: pack key-pairs, rot-16 swizzle
#pragma unroll
    for (int s2 = 0; s2 < 2; ++s2) {
      const int colw = (wave * 16 + s2 * 8 + lr + 8 * kch) & 63;
      const uint32_t* a0 = (const uint32_t*)&pv0[s2];
      const uint32_t* a1 = (const uint32_t*)&pv1[s2];
#pragma unroll
      for (int i = 0; i < 8; ++i) {
        const uint32_t w = (i & 1)
            ? __builtin_amdgcn_perm(a1[i >> 1], a0[i >> 1], 0x07060302u)
            : __builtin_amdgcn_perm(a1[i >> 1], a0[i >> 1], 0x05040100u);
        VtW[(kch * 8 + i) * 68 + colw] = w;
      }
    }
    // current kf from prefetch regs; issue next tile's kf gather + V loads
    bf16x8 kf[4];
#pragma unroll
    for (int m = 0; m < 4; ++m) kf[m] = kfn[m];
    if (kt + 1 < nktw) {
      const int kb2 = (kt + 1) * 128 + wave * 32;
#pragma unroll
      for (int m = 0; m < 4; ++m)
        kfn[m] = *(const bf16x8*)&kqv[base + (size_t)(kb2 + l32) * C3 + hD + m * 16 + hh * 8];
#pragma unroll
      for (int s2 = 0; s2 < 2; ++s2) {
        const size_t gg = base + (size_t)(kb2 + 2 * (s2 * 8 + lr)) * C3 + 2 * C + hD + kch * 8;
        pv0[s2] = *(const bf16x8*)&kqv[gg];
        pv1[s2] = *(const bf16x8*)&kqv[gg + C3];
      }
    }

    // HOISTED vf reads: qc-invariant (own-wave Vt written above, same-wave
    // DS in-order -> no barrier; not modified inside the qc loop)
    bf16x8 vf[2][2];
#pragma unroll
    for (int cc = 0; cc < 2; ++cc)
#pragma unroll
      for (int db = 0; db < 2; ++db) {
        const int d = db * 32 + l32;
        const int col = (wave * 32 + cc * 16 + hh * 8 + 16 * (d >> 3)) & 127;
        vf[cc][db] = *(const bf16x8*)&Vt[d * 136 + col];
      }

#pragma unroll
    for (int qc = 0; qc < 2; ++qc) {
      // skip: slice fully masked for this q-half (wave-uniform)
      if (key0 > qb * 64 + qc * 32 + 31) continue;
      // S^T = K·Q^T : 32 keys x 32 q; lane holds S^T[key(r,hh)][q=l32]
      f32x16 z = {};
#pragma unroll
      for (int m = 0; m < 4; ++m)
        z = __builtin_amdgcn_mfma_f32_32x32x16_bf16(kf[m], qf[qc][m], z, 0, 0, 0);
      if (key0 + 31 > qb * 64 + qc * 32) {   // diagonal band: elementwise mask
        const int qg = qb * 64 + qc * 32 + l32;
#pragma unroll
        for (int r = 0; r < 16; ++r) {
          const int kg = key0 + (r & 3) + 8 * (r >> 2) + 4 * hh;
          if (kg > qg) z[r] = -1e30f;
        }
      }
      // online softmax over this wave's 32 keys; tree max (depth 4)
      float t8[8];
#pragma unroll
      for (int r = 0; r < 8; ++r) t8[r] = fmaxf(z[r], z[r + 8]);
#pragma unroll
      for (int r = 0; r < 4; ++r) t8[r] = fmaxf(t8[r], t8[r + 4]);
      float mloc = fmaxf(fmaxf(t8[0], t8[1]), fmaxf(t8[2], t8[3]));
      mloc = fmaxf(mloc, __shfl_xor(mloc, 32, 64));
      const float pm = fmaxf(mloc * sc, -3.0e4f);   // NaN-guard floor
      if (__any(pm - m_i[qc] > 8.0f)) {   // defer-max
        const float mnew = fmaxf(m_i[qc], pm);
        const float alpha = exp2f(m_i[qc] - mnew);
#pragma unroll
        for (int r = 0; r < 16; ++r) {
          const float ar = __shfl(alpha, (r & 3) + 8 * (r >> 2) + 4 * hh, 64);
          o[qc][0][r] *= ar;
          o[qc][1][r] *= ar;
        }
        l_i[qc] *= alpha;
        m_i[qc] = mnew;
      }
#pragma unroll
      for (int r = 0; r < 16; ++r)
        z[r] = exp2f(fmaf(z[r], sc, -m_i[qc]));
      float s8[8];   // tree sum (depth 4)
#pragma unroll
      for (int r = 0; r < 8; ++r) s8[r] = z[r] + z[r + 8];
#pragma unroll
      for (int r = 0; r < 4; ++r) s8[r] += s8[r + 4];
      float rs = (s8[0] + s8[1]) + (s8[2] + s8[3]);
      rs += __shfl_xor(rs, 32, 64);
      l_i[qc] += rs;

      // O += P·V : pack P to bf16; lane-half exchange via permlane32_swap
      // (vdst.hi <-> src.lo): x' = {x.lo, y.lo}, y' = {x.hi, y.hi}
      uint32_t x0 = pkbf(z[0], z[1]),   x1 = pkbf(z[2], z[3]);
      uint32_t y0 = pkbf(z[4], z[5]),   y1 = pkbf(z[6], z[7]);
      uint32_t x2 = pkbf(z[8], z[9]),   x3 = pkbf(z[10], z[11]);
      uint32_t y2 = pkbf(z[12], z[13]), y3 = pkbf(z[14], z[15]);
      asm volatile("v_permlane32_swap_b32 %0, %1" : "+v"(x0), "+v"(y0));
      asm volatile("v_permlane32_swap_b32 %0, %1" : "+v"(x1), "+v"(y1));
      asm volatile("v_permlane32_swap_b32 %0, %1" : "+v"(x2), "+v"(y2));
      asm volatile("v_permlane32_swap_b32 %0, %1" : "+v"(x3), "+v"(y3));
#pragma unroll
      for (int cc = 0; cc < 2; ++cc) {
        union { bf16x8 v; uint32_t w[4]; } pa;
        if (cc == 0) { pa.w[0] = x0; pa.w[1] = x1; pa.w[2] = y0; pa.w[3] = y1; }
        else         { pa.w[0] = x2; pa.w[1] = x3; pa.w[2] = y2; pa.w[3] = y3; }
#pragma unroll
        for (int db = 0; db < 2; ++db)
          o[qc][db] = __builtin_amdgcn_mfma_f32_32x32x16_bf16(pa.v, vf[cc][db], o[qc][db], 0, 0, 0);
      }
    }
  }

  // ---- in-block merge of 4 per-wave partials, one qc-half at a time ----
#pragma unroll
  for (int qc = 0; qc < 2; ++qc) {
    __syncthreads();   // all waves' tiles done (qc=0) / obuf reads done (qc=1)
    if (hh == 0) {
      mlb[wave * 64 + l32] = m_i[qc];
      mlb[wave * 64 + 32 + l32] = l_i[qc];
    }
#pragma unroll
    for (int r = 0; r < 16; ++r) {
      const int ql = (r & 3) + 8 * (r >> 2) + 4 * hh;
      const int bw = wave * 2112 + ql * 66 + l32;
      obuf[bw] = o[qc][0][r];
      obuf[bw + 32] = o[qc][1][r];
    }
    __syncthreads();
    // sum phase: thread = (row q = l32, col-block cb = wave*2+hh)
    float mw[4], lw[4];
#pragma unroll
    for (int w = 0; w < 4; ++w) {
      mw[w] = mlb[w * 64 + l32];
      lw[w] = mlb[w * 64 + 32 + l32];
    }
    const float M = fmaxf(fmaxf(mw[0], mw[1]), fmaxf(mw[2], mw[3]));
    float L = 0.f, ww[4];
#pragma unroll
    for (int w = 0; w < 4; ++w) { ww[w] = exp2f(mw[w] - M); L += lw[w] * ww[w]; }
    const float Li = 1.0f / L;
    const int cb = wave * 2 + hh;
    float acc[8] = {};
#pragma unroll
    for (int w = 0; w < 4; ++w)
#pragma unroll
      for (int p = 0; p < 4; ++p) {
        const float2 v = *(const float2*)&obuf[w * 2112 + l32 * 66 + cb * 8 + p * 2];
        acc[2 * p]     += v.x * ww[w];
        acc[2 * p + 1] += v.y * ww[w];
      }
    union { bf16x8 v; uint32_t w4[4]; } ov;
#pragma unroll
    for (int p = 0; p < 4; ++p)
      ov.w4[p] = pkbf(acc[2 * p] * Li, acc[2 * p + 1] * Li);
    *(bf16x8*)&attn[((size_t)b * T + qb * 64 + qc * 32 + l32) * C + hD + cb * 8] = ov.v;
  }
}

extern "C" void kernel_launch(void* const* d_in, const int* in_sizes, int n_in,
                              void* d_out, int out_size, void* d_ws, size_t ws_size,
                              hipStream_t stream) {
  const float* x      = (const float*)d_in[0];  // (2,2048,1024) fp32
  const float* w_attn = (const float*)d_in[1];  // (3072,1024)  fp32
  const float* b_attn = (const float*)d_in[2];  // (3072,)      fp32
  const float* w_proj = (const float*)d_in[3];  // (1024,1024)  fp32
  const float* b_proj = (const float*)d_in[4];  // (1024,)      fp32
  float* out = (float*)d_out;                   // (2,2048,1024) fp32

  // ws layout (bf16): xb | wab | wpb | kqv | attnb
  uint16_t* xb    = (uint16_t*)d_ws;                     // 4096*1024
  uint16_t* wab   = xb  + (size_t)4096 * 1024;           // 3072*1024
  uint16_t* wpb   = wab + (size_t)3072 * 1024;           // 1024*1024
  uint16_t* kqv   = wpb + (size_t)1024 * 1024;           // 4096*3072
  uint16_t* attnb = kqv + (size_t)4096 * 3072;           // 4096*1024

  dim3 blk(256, 1, 1);
  hipLaunchKernelGGL(cvt_all, dim3(8192), blk, 0, stream, x, w_attn, w_proj, xb, wab, wpb);

  hipLaunchKernelGGL((gemm_bt_bias<128, 128, true>), dim3(3072 / 128, 4096 / 128, 1), blk, 0, stream,
                     xb, wab, b_attn, (void*)kqv, 4096, 3072, 1024);
  hipLaunchKernelGGL(attn_flash, dim3(1024, 1, 1), blk, 0, stream, kqv, attnb);
  hipLaunchKernelGGL((gemm_bt_bias<128, 64, false>), dim3(1024 / 64, 4096 / 128, 1), blk, 0, stream,
                     attnb, wpb, b_proj, (void*)out, 4096, 1024, 1024);
}

// Round 17
// 180.994 us; speedup vs baseline: 1.0241x; 1.0045x over previous
//
#include <hip/hip_runtime.h>
#include <hip/hip_bf16.h>
#include <cstdint>

// bf16 fragments as 8 x short (4 VGPRs) per cdna_hip_programming.md §3
typedef __attribute__((ext_vector_type(8))) short bf16x8;
typedef __attribute__((ext_vector_type(4))) float f32x4;
typedef __attribute__((ext_vector_type(16))) float f32x16;
typedef __attribute__((ext_vector_type(4))) uint16_t u16x4;

__device__ __forceinline__ uint16_t f2b(float f) {
  union { float f; uint32_t i; } v; v.f = f;
  return (uint16_t)((v.i + 0x7FFFu + ((v.i >> 16) & 1u)) >> 16);  // RNE
}

__device__ __forceinline__ uint32_t pkbf(float a, float b) {
  union { __hip_bfloat162 h2; uint32_t u; } c;
  c.h2 = __float22bfloat162_rn(make_float2(a, b));
  return c.u;   // low16 = a, high16 = b
}

// async global->LDS, 16B per lane; LDS dest is wave-uniform base + lane*16
#define GLDS16(g, l) __builtin_amdgcn_global_load_lds( \
    (const __attribute__((address_space(1))) void*)(g), \
    (__attribute__((address_space(3))) void*)(l), 16, 0, 0)

// counted vmcnt wait (literal immediate), with compiler memory fence
#define VMW(n) asm volatile("s_waitcnt vmcnt(" #n ")" ::: "memory")

// ---------------------------------------------------------------------------
// fp32 -> bf16 convert (RNE) for all three inputs in one launch
// ---------------------------------------------------------------------------
__global__ __launch_bounds__(256) void cvt_all(
    const float* __restrict__ x, const float* __restrict__ wa, const float* __restrict__ wp,
    uint16_t* __restrict__ xb, uint16_t* __restrict__ wab, uint16_t* __restrict__ wpb) {
  const int i = (blockIdx.x * 256 + threadIdx.x) * 4;
  const float* src; uint16_t* dst; int off;
  if (i < 4194304)      { src = x;  dst = xb;  off = i; }
  else if (i < 7340032) { src = wa; dst = wab; off = i - 4194304; }
  else                  { src = wp; dst = wpb; off = i - 7340032; }
  const float4 v = *(const float4*)(src + off);
  u16x4 o;
  o.x = f2b(v.x); o.y = f2b(v.y); o.z = f2b(v.z); o.w = f2b(v.w);
  *(u16x4*)(dst + off) = o;
}

// ---------------------------------------------------------------------------
// C[M,N] = A[M,K] @ B[N,K]^T + bias[N]. A,B bf16, bias fp32, fp32 accumulate.
// PIPELINED K-loop (T3+T4): BK=32, depth-2 prefetch, counted vmcnt (never 0
// in-loop) via raw s_barrier + asm. setprio(1) on MFMA (T5). Granule XOR
// swizzle (T2, rule #21) on staging source + fragment reads (2 lanes/bank).
// Buffering: bf16 path (gemm1) = 3 bufs + 2 barriers/step (verified; 48KB
// keeps 3 blocks/CU = 768-block grid granularity). fp32 path (gemm2) =
// 4 bufs + SINGLE barrier/step: with 4 buffers the end barrier is removable
// (collective barrier bounds wave skew to 1 step; writer target (s+3)%4
// never collides with live readers s%4/(s+1)%4). 48KB -> 3/CU allowed.
// Epilogues: bf16 = LDS-transposed b128 stores; fp32 = direct 64B-coalesced.
// ---------------------------------------------------------------------------
template <int BM, int BN, bool OUT_BF16>
__global__ __launch_bounds__(256, BN == 128 ? 3 : 4) void gemm_bt_bias(
    const uint16_t* __restrict__ A, const uint16_t* __restrict__ B,
    const float* __restrict__ bias, void* __restrict__ Cv,
    int M, int N, int K) {
  constexpr int MI = BM / 32;            // acc row-tiles per wave
  constexpr int NJ = BN / 32;            // acc col-tiles per wave
  constexpr int CA = BM / 16;            // A chunks per K-step (16 rows x 32K each)
  constexpr int CB = BN / 16;            // B chunks per K-step
  constexpr int CPW = (CA + CB) / 4;     // GLDS16 per thread per K-step (4 or 3)
  constexpr int ABLK = BM * 32;          // u16 per A sub-tile
  constexpr int BUFSZ = (BM + BN) * 32;  // u16 per buffer
  constexpr int NBUF = OUT_BF16 ? 3 : 4; // 4 bufs enable single-barrier steps
  constexpr size_t ST_BYTES = (size_t)NBUF * BUFSZ * 2;
  constexpr size_t CT_BYTES = OUT_BF16 ? (size_t)4 * (BM / 2) * 72 * 2 : 0;
  constexpr size_t LB = CT_BYTES > ST_BYTES ? CT_BYTES : ST_BYTES;
  __shared__ alignas(16) unsigned char ldsb[LB];
  uint16_t* lds = (uint16_t*)ldsb;

  const int tid = threadIdx.x;
  const int wave = tid >> 6, lane = tid & 63;
  const int q4 = lane >> 4, l16 = lane & 15;
  const int wm = wave >> 1, wn = wave & 1;
  const long blockM = (long)blockIdx.y * BM;
  const long blockN = (long)blockIdx.x * BN;
  const int NK = K >> 5;                 // K-steps of 32

  f32x4 acc[MI][NJ] = {};

  auto STAGE = [&](int s) {
    uint16_t* buf = lds + (s % NBUF) * BUFSZ;
#pragma unroll
    for (int c = 0; c < CPW; ++c) {
      const int id = c * 4 + wave;       // wave-uniform
      const uint16_t* mat; long rowBase; int a, off;
      if (id < CA) { mat = A; rowBase = blockM; a = id;      off = a * 512; }
      else         { mat = B; rowBase = blockN; a = id - CA; off = ABLK + a * 512; }
      const int flat = a * 64 + lane;
      const int row = flat >> 2;
      const int seg = (flat & 3) ^ ((flat >> 3) & 3);   // pre-swizzled source
      GLDS16(mat + (rowBase + row) * (long)K + s * 32 + seg * 8, buf + off);
    }
  };

  STAGE(0);
  STAGE(1);
  for (int s = 0; s < NK; ++s) {
    if (s + 2 < NK) STAGE(s + 2);
    __builtin_amdgcn_sched_barrier(0);
    if (s + 2 < NK) {                    // outstanding: stage(s+1), stage(s+2)
      if constexpr (CPW == 4) VMW(8); else VMW(6);
    } else if (s + 2 == NK) {            // outstanding: stage(s+1)
      if constexpr (CPW == 4) VMW(4); else VMW(3);
    } else {
      VMW(0);
    }
    __builtin_amdgcn_sched_barrier(0);
    __builtin_amdgcn_s_barrier();        // everyone's stage(s) landed
    const uint16_t* Ah = lds + (s % NBUF) * BUFSZ;
    const uint16_t* Bh = Ah + ABLK;
    bf16x8 af[MI], bfr[NJ];
#pragma unroll
    for (int i = 0; i < MI; ++i) {
      const int row = wm * (BM / 2) + i * 16 + l16;
      const int g = q4 ^ ((row >> 1) & 3);             // swizzled granule
      af[i] = *(const bf16x8*)&Ah[row * 32 + g * 8];
    }
#pragma unroll
    for (int j = 0; j < NJ; ++j) {
      const int row = wn * (BN / 2) + j * 16 + l16;
      const int g = q4 ^ ((row >> 1) & 3);
      bfr[j] = *(const bf16x8*)&Bh[row * 32 + g * 8];
    }
    __builtin_amdgcn_s_setprio(1);
#pragma unroll
    for (int i = 0; i < MI; ++i)
#pragma unroll
      for (int j = 0; j < NJ; ++j)
        acc[i][j] = __builtin_amdgcn_mfma_f32_16x16x32_bf16(af[i], bfr[j], acc[i][j], 0, 0, 0);
    __builtin_amdgcn_s_setprio(0);
    if constexpr (OUT_BF16)
      __builtin_amdgcn_s_barrier();      // 3-buf path: restage needs reads done
  }
  __syncthreads();                       // full drain before LDS reuse / exit

  // epilogue: acc (C/D layout: col=l16, row=q4*4+r)
  if constexpr (OUT_BF16) {
    // LDS-transposed vector stores (BN=128 path, verified)
    uint16_t* ct = lds + wave * (BM / 2) * 72;
#pragma unroll
    for (int j = 0; j < NJ; ++j) {
      const float bv = bias[blockN + wn * (BN / 2) + j * 16 + l16];
#pragma unroll
      for (int i = 0; i < MI; ++i)
#pragma unroll
        for (int r = 0; r < 4; ++r)
          ct[(i * 16 + q4 * 4 + r) * 72 + j * 16 + l16] = f2b(acc[i][j][r] + bv);
    }
    __syncthreads();
    uint16_t* Cb = (uint16_t*)Cv;
#pragma unroll
    for (int st = 0; st < BM / 16; ++st) {
      const int flat = st * 64 + lane;
      const int row = flat >> 3, seg = flat & 7;
      const bf16x8 v = *(const bf16x8*)&ct[row * 72 + seg * 8];
      *(bf16x8*)&Cb[(blockM + wm * (BM / 2) + row) * (long)N + blockN + wn * 64 + seg * 8] = v;
    }
  } else {
    // direct fp32 stores: quad q4 writes 16 consecutive cols (64B segments)
    float* Cb = (float*)Cv;
#pragma unroll
    for (int j = 0; j < NJ; ++j) {
      const long col = blockN + wn * (BN / 2) + j * 16 + l16;
      const float bv = bias[col];
#pragma unroll
      for (int i = 0; i < MI; ++i)
#pragma unroll
        for (int r = 0; r < 4; ++r) {
          const long row = blockM + wm * (BM / 2) + i * 16 + q4 * 4 + r;
          Cb[row * (long)N + col] = acc[i][j][r] + bv;
        }
    }
  }
}

// ---------------------------------------------------------------------------
// Flash-style causal attention, S^T form, 32x32x16 MFMA, in-block split-K,
// barrier-free tiles, direct-from-L2 K fragments, hoisted qc-invariant vf
// reads (r16: conflicts 3.21M->2.16M). NEW this round:
//  * SINGLE merged merge-phase: obuf holds BOTH qc halves (disjoint
//    buffers -> qc0-read/qc1-write hazard gone); 4 barriers + 2 phases
//    -> 2 barriers + 1 phase. LDS 69.6KB, still 2 blocks/CU.
//  * max reduction as nested fmax triples (clang fuses to v_max3_f32).
// V path / softmax / permlane P-exchange unchanged (r11/r16-verified).
// NaN guard: pm floored at -3e4. bh in LOW bits for XCD L2 locality.
// ---------------------------------------------------------------------------
__global__ __launch_bounds__(256, 2) void attn_flash(
    const uint16_t* __restrict__ kqv, uint16_t* __restrict__ attn) {
  constexpr int T = 2048, C = 1024, C3 = 3072;
  __shared__ alignas(16) unsigned char ldsb[69632];
  uint16_t* Vt = (uint16_t*)ldsb;             // [64][136] u16, rot-16 swizzle
  uint32_t* VtW = (uint32_t*)ldsb;            // pitch 68 dwords
  float* mlb  = (float*)ldsb;                 // [4][2qc][2][32] (merge overlay)
  float* obuf = (float*)(ldsb + 2048);        // [4][2qc][32][66] f32 (merge overlay)

  const int tid = threadIdx.x;
  const int wave = tid >> 6, lane = tid & 63;
  const int l32 = lane & 31, hh = lane >> 5;
  const int sidx = blockIdx.x >> 5, bh = blockIdx.x & 31;
  const int b = bh >> 4, h = bh & 15;
  const size_t base = (size_t)b * T * C3;
  const int hD = h * 64;
  const int lr = lane >> 3, kch = lane & 7;   // per-wave V staging coords
  const float sc = 0.125f * 1.4426950408889634f;  // D^-0.5 * log2(e)

  const int qb = 31 - sidx;            // big strips first (backfill order)
  const int dd = qb * 64 + 63 - wave * 32;
  const int nktw = (dd < 0) ? 0 : ((dd >> 7) + 1);

  // Q regs: qf[qc][m], B-frag col=l32, k=hh*8+j
  bf16x8 qf[2][4];
#pragma unroll
  for (int qc = 0; qc < 2; ++qc)
#pragma unroll
    for (int m = 0; m < 4; ++m)
      qf[qc][m] = *(const bf16x8*)&kqv[base + (size_t)(qb * 64 + qc * 32 + l32) * C3 + C + hD + m * 16 + hh * 8];

  f32x16 o[2][2] = {};   // [qc][db]: O[q=qc*32+(r&3)+8*(r>>2)+4*hh][d=db*32+l32]
  float m_i[2] = {-1e30f, -1e30f}, l_i[2] = {0.f, 0.f};

  // prefetch own slice of tile 0: kf directly (gather), V for LDS transpose
  bf16x8 kfn[4], pv0[2], pv1[2];
  if (nktw > 0) {
    const int kb0 = wave * 32;
#pragma unroll
    for (int m = 0; m < 4; ++m)
      kfn[m] = *(const bf16x8*)&kqv[base + (size_t)(kb0 + l32) * C3 + hD + m * 16 + hh * 8];
#pragma unroll
    for (int s2 = 0; s2 < 2; ++s2) {
      const size_t gg = base + (size_t)(kb0 + 2 * (s2 * 8 + lr)) * C3 + 2 * C + hD + kch * 8;
      pv0[s2] = *(const bf16x8*)&kqv[gg];
      pv1[s2] = *(const bf16x8*)&kqv[gg + C3];
    }
  }

  for (int kt = 0; kt < nktw; ++kt) {
    const int key0 = kt * 128 + wave * 32;
    // stage own V slice transposed: pack key-pairs, rot-16 swizzle
#pragma unroll
    for (int s2 = 0; s2 < 2; ++s2) {
      const int colw = (wave * 16 + s2 * 8 + lr + 8 * kch) & 63;
      const uint32_t* a0 = (const uint32_t*)&pv0[s2];
      const uint32_t* a1 = (const uint32_t*)&pv1[s2];
#pragma unroll
      for (int i = 0; i < 8; ++i) {
        const uint32_t w = (i & 1)
            ? __builtin_amdgcn_perm(a1[i >> 1], a0[i >> 1], 0x07060302u)
            : __builtin_amdgcn_perm(a1[i >> 1], a0[i >> 1], 0x05040100u);
        VtW[(kch * 8 + i) * 68 + colw] = w;
      }
    }
    // current kf from prefetch regs; issue next tile's kf gather + V loads
    bf16x8 kf[4];
#pragma unroll
    for (int m = 0; m < 4; ++m) kf[m] = kfn[m];
    if (kt + 1 < nktw) {
      const int kb2 = (kt + 1) * 128 + wave * 32;
#pragma unroll
      for (int m = 0; m < 4; ++m)
        kfn[m] = *(const bf16x8*)&kqv[base + (size_t)(kb2 + l32) * C3 + hD + m * 16 + hh * 8];
#pragma unroll
      for (int s2 = 0; s2 < 2; ++s2) {
        const size_t gg = base + (size_t)(kb2 + 2 * (s2 * 8 + lr)) * C3 + 2 * C + hD + kch * 8;
        pv0[s2] = *(const bf16x8*)&kqv[gg];
        pv1[s2] = *(const bf16x8*)&kqv[gg + C3];
      }
    }

    // HOISTED vf reads: qc-invariant (own-wave Vt written above, same-wave
    // DS in-order -> no barrier; not modified inside the qc loop)
    bf16x8 vf[2][2];
#pragma unroll
    for (int cc = 0; cc < 2; ++cc)
#pragma unroll
      for (int db = 0; db < 2; ++db) {
        const int d = db * 32 + l32;
        const int col = (wave * 32 + cc * 16 + hh * 8 + 16 * (d >> 3)) & 127;
        vf[cc][db] = *(const bf16x8*)&Vt[d * 136 + col];
      }

#pragma unroll
    for (int qc = 0; qc < 2; ++qc) {
      // skip: slice fully masked for this q-half (wave-uniform)
      if (key0 > qb * 64 + qc * 32 + 31) continue;
      // S^T = K·Q^T : 32 keys x 32 q; lane holds S^T[key(r,hh)][q=l32]
      f32x16 z = {};
#pragma unroll
      for (int m = 0; m < 4; ++m)
        z = __builtin_amdgcn_mfma_f32_32x32x16_bf16(kf[m], qf[qc][m], z, 0, 0, 0);
      if (key0 + 31 > qb * 64 + qc * 32) {   // diagonal band: elementwise mask
        const int qg = qb * 64 + qc * 32 + l32;
#pragma unroll
        for (int r = 0; r < 16; ++r) {
          const int kg = key0 + (r & 3) + 8 * (r >> 2) + 4 * hh;
          if (kg > qg) z[r] = -1e30f;
        }
      }
      // online softmax; max via nested triples (v_max3 fusion)
      const float a0m = fmaxf(fmaxf(z[0], z[1]), z[2]);
      const float a1m = fmaxf(fmaxf(z[3], z[4]), z[5]);
      const float a2m = fmaxf(fmaxf(z[6], z[7]), z[8]);
      const float a3m = fmaxf(fmaxf(z[9], z[10]), z[11]);
      const float a4m = fmaxf(fmaxf(z[12], z[13]), z[14]);
      float mloc = fmaxf(fmaxf(fmaxf(a0m, a1m), a2m), fmaxf(fmaxf(a3m, a4m), z[15]));
      mloc = fmaxf(mloc, __shfl_xor(mloc, 32, 64));
      const float pm = fmaxf(mloc * sc, -3.0e4f);   // NaN-guard floor
      if (__any(pm - m_i[qc] > 8.0f)) {   // defer-max
        const float mnew = fmaxf(m_i[qc], pm);
        const float alpha = exp2f(m_i[qc] - mnew);
#pragma unroll
        for (int r = 0; r < 16; ++r) {
          const float ar = __shfl(alpha, (r & 3) + 8 * (r >> 2) + 4 * hh, 64);
          o[qc][0][r] *= ar;
          o[qc][1][r] *= ar;
        }
        l_i[qc] *= alpha;
        m_i[qc] = mnew;
      }
#pragma unroll
      for (int r = 0; r < 16; ++r)
        z[r] = exp2f(fmaf(z[r], sc, -m_i[qc]));
      float s8[8];   // tree sum (depth 4)
#pragma unroll
      for (int r = 0; r < 8; ++r) s8[r] = z[r] + z[r + 8];
#pragma unroll
      for (int r = 0; r < 4; ++r) s8[r] += s8[r + 4];
      float rs = (s8[0] + s8[1]) + (s8[2] + s8[3]);
      rs += __shfl_xor(rs, 32, 64);
      l_i[qc] += rs;

      // O += P·V : pack P to bf16; lane-half exchange via permlane32_swap
      // (vdst.hi <-> src.lo): x' = {x.lo, y.lo}, y' = {x.hi, y.hi}
      uint32_t x0 = pkbf(z[0], z[1]),   x1 = pkbf(z[2], z[3]);
      uint32_t y0 = pkbf(z[4], z[5]),   y1 = pkbf(z[6], z[7]);
      uint32_t x2 = pkbf(z[8], z[9]),   x3 = pkbf(z[10], z[11]);
      uint32_t y2 = pkbf(z[12], z[13]), y3 = pkbf(z[14], z[15]);
      asm volatile("v_permlane32_swap_b32 %0, %1" : "+v"(x0), "+v"(y0));
      asm volatile("v_permlane32_swap_b32 %0, %1" : "+v"(x1), "+v"(y1));
      asm volatile("v_permlane32_swap_b32 %0, %1" : "+v"(x2), "+v"(y2));
      asm volatile("v_permlane32_swap_b32 %0, %1" : "+v"(x3), "+v"(y3));
#pragma unroll
      for (int cc = 0; cc < 2; ++cc) {
        union { bf16x8 v; uint32_t w[4]; } pa;
        if (cc == 0) { pa.w[0] = x0; pa.w[1] = x1; pa.w[2] = y0; pa.w[3] = y1; }
        else         { pa.w[0] = x2; pa.w[1] = x3; pa.w[2] = y2; pa.w[3] = y3; }
#pragma unroll
        for (int db = 0; db < 2; ++db)
          o[qc][db] = __builtin_amdgcn_mfma_f32_32x32x16_bf16(pa.v, vf[cc][db], o[qc][db], 0, 0, 0);
      }
    }
  }

  // ---- in-block merge of 4 per-wave partials, BOTH qc halves in one pass ----
  __syncthreads();   // all waves' tiles done -> Vt region reusable as obuf
#pragma unroll
  for (int qc = 0; qc < 2; ++qc) {
    if (hh == 0) {
      mlb[wave * 128 + qc * 64 + l32] = m_i[qc];
      mlb[wave * 128 + qc * 64 + 32 + l32] = l_i[qc];
    }
#pragma unroll
    for (int r = 0; r < 16; ++r) {
      const int ql = (r & 3) + 8 * (r >> 2) + 4 * hh;
      const int bw = wave * 4224 + qc * 2112 + ql * 66 + l32;
      obuf[bw] = o[qc][0][r];
      obuf[bw + 32] = o[qc][1][r];
    }
  }
  __syncthreads();
  // sum phase: thread = (row q = l32, col-block cb = wave*2+hh), both qc
#pragma unroll
  for (int qc = 0; qc < 2; ++qc) {
    float mw[4], lw[4];
#pragma unroll
    for (int w = 0; w < 4; ++w) {
      mw[w] = mlb[w * 128 + qc * 64 + l32];
      lw[w] = mlb[w * 128 + qc * 64 + 32 + l32];
    }
    const float M = fmaxf(fmaxf(mw[0], mw[1]), fmaxf(mw[2], mw[3]));
    float L = 0.f, ww[4];
#pragma unroll
    for (int w = 0; w < 4; ++w) { ww[w] = exp2f(mw[w] - M); L += lw[w] * ww[w]; }
    const float Li = 1.0f / L;
    const int cb = wave * 2 + hh;
    float acc[8] = {};
#pragma unroll
    for (int w = 0; w < 4; ++w)
#pragma unroll
      for (int p = 0; p < 4; ++p) {
        const float2 v = *(const float2*)&obuf[w * 4224 + qc * 2112 + l32 * 66 + cb * 8 + p * 2];
        acc[2 * p]     += v.x * ww[w];
        acc[2 * p + 1] += v.y * ww[w];
      }
    union { bf16x8 v; uint32_t w4[4]; } ov;
#pragma unroll
    for (int p = 0; p < 4; ++p)
      ov.w4[p] = pkbf(acc[2 * p] * Li, acc[2 * p + 1] * Li);
    *(bf16x8*)&attn[((size_t)b * T + qb * 64 + qc * 32 + l32) * C + hD + cb * 8] = ov.v;
  }
}

extern "C" void kernel_launch(void* const* d_in, const int* in_sizes, int n_in,
                              void* d_out, int out_size, void* d_ws, size_t ws_size,
                              hipStream_t stream) {
  const float* x      = (const float*)d_in[0];  // (2,2048,1024) fp32
  const float* w_attn = (const float*)d_in[1];  // (3072,1024)  fp32
  const float* b_attn = (const float*)d_in[2];  // (3072,)      fp32
  const float* w_proj = (const float*)d_in[3];  // (1024,1024)  fp32
  const float* b_proj = (const float*)d_in[4];  // (1024,)      fp32
  float* out = (float*)d_out;                   // (2,2048,1024) fp32

  // ws layout (bf16): xb | wab | wpb | kqv | attnb
  uint16_t* xb    = (uint16_t*)d_ws;                     // 4096*1024
  uint16_t* wab   = xb  + (size_t)4096 * 1024;           // 3072*1024
  uint16_t* wpb   = wab + (size_t)3072 * 1024;           // 1024*1024
  uint16_t* kqv   = wpb + (size_t)1024 * 1024;           // 4096*3072
  uint16_t* attnb = kqv + (size_t)4096 * 3072;           // 4096*1024

  dim3 blk(256, 1, 1);
  hipLaunchKernelGGL(cvt_all, dim3(8192), blk, 0, stream, x, w_attn, w_proj, xb, wab, wpb);

  hipLaunchKernelGGL((gemm_bt_bias<128, 128, true>), dim3(3072 / 128, 4096 / 128, 1), blk, 0, stream,
                     xb, wab, b_attn, (void*)kqv, 4096, 3072, 1024);
  hipLaunchKernelGGL(attn_flash, dim3(1024, 1, 1), blk, 0, stream, kqv, attnb);
  hipLaunchKernelGGL((gemm_bt_bias<128, 64, false>), dim3(1024 / 64, 4096 / 128, 1), blk, 0, stream,
                     attnb, wpb, b_proj, (void*)out, 4096, 1024, 1024);
}